// Round 2
// baseline (719.283 us; speedup 1.0000x reference)
//
#include <hip/hip_runtime.h>
#include <stdint.h>
#include <math.h>

#define D 128

// ---- Stage A: degree / dinv / CSR build ----

__global__ void k_degree(const int* __restrict__ dst, int E, int* __restrict__ degi) {
    int i = blockIdx.x * blockDim.x + threadIdx.x;
    if (i < E) atomicAdd(&degi[dst[i]], 1);
}

__global__ void k_dinv(const int* __restrict__ degi, float* __restrict__ dinv, int N) {
    int i = blockIdx.x * blockDim.x + threadIdx.x;
    if (i < N) dinv[i] = rsqrtf((float)degi[i] + 1.0f);
}

// single-block exclusive scan of degi -> rowstart[0..N]
__global__ void k_scan(const int* __restrict__ degi, int* __restrict__ rowstart, int n) {
    __shared__ int sums[1024];
    int t = threadIdx.x;
    int chunk = (n + 1023) >> 10;
    if (chunk < 1) chunk = 1;
    int lo = t * chunk;
    int hi = lo + chunk; if (hi > n) hi = n;
    int s = 0;
    for (int i = lo; i < hi; ++i) s += degi[i];
    sums[t] = s;
    __syncthreads();
    for (int off = 1; off < 1024; off <<= 1) {
        int v = (t >= off) ? sums[t - off] : 0;
        __syncthreads();
        if (t >= off) sums[t] += v;
        __syncthreads();
    }
    int run = (t == 0) ? 0 : sums[t - 1];
    for (int i = lo; i < hi; ++i) { rowstart[i] = run; run += degi[i]; }
    if (hi == n) rowstart[n] = run;   // all tail threads write the same total E
}

__global__ void k_scatter(const int* __restrict__ src, const int* __restrict__ dst, int E,
                          const int* __restrict__ rowstart, int* __restrict__ cursor,
                          int* __restrict__ col) {
    int i = blockIdx.x * blockDim.x + threadIdx.x;
    if (i < E) {
        int d = dst[i];
        int pos = rowstart[d] + atomicAdd(&cursor[d], 1);
        col[pos] = src[i];
    }
}

// ---- Stage B: layer-1 transform  g1 = dinv * (x @ W1),  x:[N,8] f32 ----

__global__ __launch_bounds__(256) void k_xform1(const float* __restrict__ x, const float* __restrict__ W1,
                                                const float* __restrict__ dinv, float* __restrict__ g, int N) {
    __shared__ float Ws[8 * D];
    int t = threadIdx.x;
    for (int i = t; i < 8 * D; i += 256) Ws[i] = W1[i];
    __syncthreads();
    int node = blockIdx.x * 2 + (t >> 7);
    int f = t & 127;
    if (node < N) {
        const float* xp = x + node * 8;
        float s = 0.f;
#pragma unroll
        for (int k = 0; k < 8; ++k) s += xp[k] * Ws[k * D + f];
        g[node * D + f] = s * dinv[node];
    }
}

// ---- Aggregation: one wave per node, CSR gather-sum; h = relu(dinv*(self+sum) + b) ----

__global__ __launch_bounds__(256) void k_agg(const float* __restrict__ g, const int* __restrict__ rowstart,
                                             const int* __restrict__ col, const float* __restrict__ dinv,
                                             const float* __restrict__ bias, float* __restrict__ h, int N) {
    int wave = (blockIdx.x * blockDim.x + threadIdx.x) >> 6;
    int lane = threadIdx.x & 63;
    if (wave >= N) return;
    int i = wave;
    const float2* gp = (const float2*)g;
    float2 acc = gp[i * 64 + lane];   // self term g[i]
    int lo = rowstart[i], hi = rowstart[i + 1];
    for (int base = lo; base < hi; base += 64) {
        int idx = base + lane;
        int myc = (idx < hi) ? col[idx] : 0;
        int cnt = hi - base; if (cnt > 64) cnt = 64;
        for (int j = 0; j < cnt; ++j) {
            int s = __shfl(myc, j, 64);
            float2 v = gp[s * 64 + lane];
            acc.x += v.x; acc.y += v.y;
        }
    }
    float di = dinv[i];
    float b0 = bias[2 * lane];
    float b1 = bias[2 * lane + 1];
    float r0 = fmaxf(acc.x * di + b0, 0.f);
    float r1 = fmaxf(acc.y * di + b1, 0.f);
    ((float2*)h)[i * 64 + lane] = make_float2(r0, r1);
}

// ---- Generic node GEMM: out[n,f] = (in[n,:] @ W[:,f]) * (dinv?) + (bias?)  W:[128,128] f32 ----
// block: 64 nodes x 64 f-columns (f-half selected by blockIdx.x&1); thread: 4x4 register tile

#define GEMM_NPB 64
__global__ __launch_bounds__(256) void k_gemm128(const float* __restrict__ W, const float* __restrict__ in,
                                                 const float* __restrict__ bias, const float* __restrict__ dinv,
                                                 float* __restrict__ out, int N) {
    __shared__ float Ws[D * 64];       // Ws[k*64+fl] = W[k*128 + fbase+fl]   (32 KB)
    __shared__ float hs[GEMM_NPB * D]; // hs[j*128+k]                          (32 KB)
    int t = threadIdx.x;
    int fbase = (blockIdx.x & 1) << 6;
    int base = (blockIdx.x >> 1) * GEMM_NPB;
    for (int i = t; i < D * 64; i += 256) {
        int k = i >> 6, fl = i & 63;
        Ws[i] = W[(k << 7) + fbase + fl];
    }
    for (int i = t; i < GEMM_NPB * D; i += 256) {
        int node = base + (i >> 7);
        hs[i] = (node < N) ? in[node * D + (i & 127)] : 0.f;
    }
    __syncthreads();
    int tf = (t & 15) << 2;   // f-quad
    int tj = (t >> 4) << 2;   // node-quad
    float acc[4][4];
#pragma unroll
    for (int a = 0; a < 4; ++a)
#pragma unroll
        for (int b = 0; b < 4; ++b) acc[a][b] = 0.f;
    for (int k = 0; k < D; k += 4) {
        float4 w[4];
        float4 hv[4];
#pragma unroll
        for (int kk = 0; kk < 4; ++kk) w[kk] = *(const float4*)&Ws[(k + kk) * 64 + tf];
#pragma unroll
        for (int j = 0; j < 4; ++j) hv[j] = *(const float4*)&hs[(tj + j) * D + k];
#pragma unroll
        for (int j = 0; j < 4; ++j) {
            float hk0 = hv[j].x, hk1 = hv[j].y, hk2 = hv[j].z, hk3 = hv[j].w;
            acc[j][0] += hk0 * w[0].x + hk1 * w[1].x + hk2 * w[2].x + hk3 * w[3].x;
            acc[j][1] += hk0 * w[0].y + hk1 * w[1].y + hk2 * w[2].y + hk3 * w[3].y;
            acc[j][2] += hk0 * w[0].z + hk1 * w[1].z + hk2 * w[2].z + hk3 * w[3].z;
            acc[j][3] += hk0 * w[0].w + hk1 * w[1].w + hk2 * w[2].w + hk3 * w[3].w;
        }
    }
    float bv0 = 0.f, bv1 = 0.f, bv2 = 0.f, bv3 = 0.f;
    if (bias) {
        bv0 = bias[fbase + tf + 0];
        bv1 = bias[fbase + tf + 1];
        bv2 = bias[fbase + tf + 2];
        bv3 = bias[fbase + tf + 3];
    }
#pragma unroll
    for (int j = 0; j < 4; ++j) {
        int node = base + tj + j;
        if (node >= N) continue;
        float sc = dinv ? dinv[node] : 1.0f;
        float4 o;
        o.x = acc[j][0] * sc + bv0;
        o.y = acc[j][1] * sc + bv1;
        o.z = acc[j][2] * sc + bv2;
        o.w = acc[j][3] * sc + bv3;
        *(float4*)&out[node * D + fbase + tf] = o;
    }
}

// ---- Edge output: z = relu(a[src]+c[dst]); logits = z@Wfin + bfin; log_softmax ----

__global__ __launch_bounds__(256) void k_edge(const float* __restrict__ a, const float* __restrict__ c,
                                              const int* __restrict__ src, const int* __restrict__ dst,
                                              const float* __restrict__ Wfin, const float* __restrict__ bfin,
                                              float* __restrict__ out, int E) {
    int gwave = (blockIdx.x * blockDim.x + threadIdx.x) >> 6;
    int lane = threadIdx.x & 63;
    int nwaves = (gridDim.x * blockDim.x) >> 6;
    // lane holds Wfin rows 2*lane, 2*lane+1 (each 2 classes)
    float w00 = Wfin[4 * lane + 0];
    float w01 = Wfin[4 * lane + 1];
    float w10 = Wfin[4 * lane + 2];
    float w11 = Wfin[4 * lane + 3];
    float bf0 = bfin[0], bf1 = bfin[1];
    const float2* ap = (const float2*)a;
    const float2* cp = (const float2*)c;
    for (int e = gwave; e < E; e += nwaves) {
        int s = src[e], d = dst[e];
        float2 av = ap[s * 64 + lane];
        float2 cv = cp[d * 64 + lane];
        float z0 = fmaxf(av.x + cv.x, 0.f);
        float z1 = fmaxf(av.y + cv.y, 0.f);
        float p0 = z0 * w00 + z1 * w10;
        float p1 = z0 * w01 + z1 * w11;
#pragma unroll
        for (int off = 32; off > 0; off >>= 1) {
            p0 += __shfl_xor(p0, off, 64);
            p1 += __shfl_xor(p1, off, 64);
        }
        if (lane == 0) {
            float l0 = p0 + bf0, l1 = p1 + bf1;
            float m = fmaxf(l0, l1);
            float lse = m + logf(expf(l0 - m) + expf(l1 - m));
            *((float2*)(out + 2 * (size_t)e)) = make_float2(l0 - lse, l1 - lse);
        }
    }
}

extern "C" void kernel_launch(void* const* d_in, const int* in_sizes, int n_in,
                              void* d_out, int out_size, void* d_ws, size_t ws_size,
                              hipStream_t stream) {
    const float* x     = (const float*)d_in[0];
    const int*   ei    = (const int*)d_in[1];
    const float* W1    = (const float*)d_in[2];
    const float* b1    = (const float*)d_in[3];
    const float* W2    = (const float*)d_in[4];
    const float* b2    = (const float*)d_in[5];
    const float* Wlin1 = (const float*)d_in[6];
    const float* blin1 = (const float*)d_in[7];
    const float* Wfin  = (const float*)d_in[8];
    const float* bfin  = (const float*)d_in[9];
    float* out = (float*)d_out;

    int N = in_sizes[0] / 8;
    int E = in_sizes[1] / 2;
    const int* src = ei;
    const int* dst = ei + E;

    char* w = (char*)d_ws;
    int* degi = (int*)w;      w += (size_t)N * 4;
    int* cursor = (int*)w;    w += (size_t)N * 4;
    int* rowstart = (int*)w;  w += (size_t)(N + 1) * 4;
    int* col = (int*)w;       w += (size_t)E * 4;
    float* dinv = (float*)w;  w += (size_t)N * 4;
    w = (char*)(((uintptr_t)w + 255) & ~(uintptr_t)255);
    float* buf0 = (float*)w;  w += (size_t)N * D * 4;
    float* buf1 = (float*)w;  w += (size_t)N * D * 4;
    float* buf2 = (float*)w;  w += (size_t)N * D * 4;

    // zero degi + cursor (contiguous)
    hipMemsetAsync(degi, 0, (size_t)N * 8, stream);

    k_degree<<<(E + 255) / 256, 256, 0, stream>>>(dst, E, degi);
    k_dinv<<<(N + 255) / 256, 256, 0, stream>>>(degi, dinv, N);
    k_scan<<<1, 1024, 0, stream>>>(degi, rowstart, N);
    k_scatter<<<(E + 255) / 256, 256, 0, stream>>>(src, dst, E, rowstart, cursor, col);

    // layer 1: g1 = dinv*(x@W1) -> buf0 ; h1 = relu(dinv*(self+sum)+b1) -> buf1
    k_xform1<<<(N + 1) / 2, 256, 0, stream>>>(x, W1, dinv, buf0, N);
    k_agg<<<(N + 3) / 4, 256, 0, stream>>>(buf0, rowstart, col, dinv, b1, buf1, N);

    // layer 2: g2 = dinv*(h1@W2) -> buf0 ; h2 -> buf1
    int gblocks = ((N + GEMM_NPB - 1) / GEMM_NPB) * 2;
    k_gemm128<<<gblocks, 256, 0, stream>>>(W2, buf1, nullptr, dinv, buf0, N);
    k_agg<<<(N + 3) / 4, 256, 0, stream>>>(buf0, rowstart, col, dinv, b2, buf1, N);

    // edge MLP factorization: a = h2@Wtop -> buf0 ; c = h2@Wbot + blin1 -> buf2
    k_gemm128<<<gblocks, 256, 0, stream>>>(Wlin1, buf1, nullptr, nullptr, buf0, N);
    k_gemm128<<<gblocks, 256, 0, stream>>>(Wlin1 + D * D, buf1, blin1, nullptr, buf2, N);

    k_edge<<<4096, 256, 0, stream>>>(buf0, buf2, src, dst, Wfin, bfin, out, E);
}

// Round 3
// 696.752 us; speedup vs baseline: 1.0323x; 1.0323x over previous
//
#include <hip/hip_runtime.h>
#include <stdint.h>
#include <math.h>

#define D 128

// ---- Stage A: degree / dinv / CSR build ----

__global__ void k_degree(const int* __restrict__ dst, int E, int* __restrict__ degi) {
    int i = blockIdx.x * blockDim.x + threadIdx.x;
    if (i < E) atomicAdd(&degi[dst[i]], 1);
}

__global__ void k_dinv(const int* __restrict__ degi, float* __restrict__ dinv, int N) {
    int i = blockIdx.x * blockDim.x + threadIdx.x;
    if (i < N) dinv[i] = rsqrtf((float)degi[i] + 1.0f);
}

// single-block exclusive scan of degi -> rowstart[0..N]
__global__ void k_scan(const int* __restrict__ degi, int* __restrict__ rowstart, int n) {
    __shared__ int sums[1024];
    int t = threadIdx.x;
    int chunk = (n + 1023) >> 10;
    if (chunk < 1) chunk = 1;
    int lo = t * chunk;
    int hi = lo + chunk; if (hi > n) hi = n;
    int s = 0;
    for (int i = lo; i < hi; ++i) s += degi[i];
    sums[t] = s;
    __syncthreads();
    for (int off = 1; off < 1024; off <<= 1) {
        int v = (t >= off) ? sums[t - off] : 0;
        __syncthreads();
        if (t >= off) sums[t] += v;
        __syncthreads();
    }
    int run = (t == 0) ? 0 : sums[t - 1];
    for (int i = lo; i < hi; ++i) { rowstart[i] = run; run += degi[i]; }
    if (hi == n) rowstart[n] = run;
}

__global__ void k_scatter(const int* __restrict__ src, const int* __restrict__ dst, int E,
                          const int* __restrict__ rowstart, int* __restrict__ cursor,
                          int* __restrict__ col, int* __restrict__ eid) {
    int i = blockIdx.x * blockDim.x + threadIdx.x;
    if (i < E) {
        int d = dst[i];
        int pos = rowstart[d] + atomicAdd(&cursor[d], 1);
        col[pos] = src[i];
        eid[pos] = i;
    }
}

// ---- Stage B: layer-1 transform  g1 = dinv * (x @ W1),  x:[N,8] f32 ----

__global__ __launch_bounds__(256) void k_xform1(const float* __restrict__ x, const float* __restrict__ W1,
                                                const float* __restrict__ dinv, float* __restrict__ g, int N) {
    __shared__ float Ws[8 * D];
    int t = threadIdx.x;
    for (int i = t; i < 8 * D; i += 256) Ws[i] = W1[i];
    __syncthreads();
    int node = blockIdx.x * 2 + (t >> 7);
    int f = t & 127;
    if (node < N) {
        const float* xp = x + node * 8;
        float s = 0.f;
#pragma unroll
        for (int k = 0; k < 8; ++k) s += xp[k] * Ws[k * D + f];
        g[node * D + f] = s * dinv[node];
    }
}

// ---- Aggregation: one wave per node; 32-lane halves process neighbor pairs with float4 loads ----
// h = relu(dinv*(self+sum) + b)

__global__ __launch_bounds__(256) void k_agg(const float* __restrict__ g, const int* __restrict__ rowstart,
                                             const int* __restrict__ col, const float* __restrict__ dinv,
                                             const float* __restrict__ bias, float* __restrict__ h, int N) {
    int wave = (blockIdx.x * blockDim.x + threadIdx.x) >> 6;
    int lane = threadIdx.x & 63;
    if (wave >= N) return;
    int i = wave;
    int sub = lane >> 5;      // which neighbor of the pair
    int l = lane & 31;        // float4 slot within row
    const float4* g4 = (const float4*)g;
    float4 acc = make_float4(0.f, 0.f, 0.f, 0.f);
    int lo = rowstart[i], hi = rowstart[i + 1];
    for (int base = lo; base < hi; base += 2) {
        int idx = base + sub;
        if (idx < hi) {
            int s = col[idx];
            float4 v = g4[s * 32 + l];
            acc.x += v.x; acc.y += v.y; acc.z += v.z; acc.w += v.w;
        }
    }
    // combine the two halves
    acc.x += __shfl_xor(acc.x, 32, 64);
    acc.y += __shfl_xor(acc.y, 32, 64);
    acc.z += __shfl_xor(acc.z, 32, 64);
    acc.w += __shfl_xor(acc.w, 32, 64);
    if (sub == 0) {
        float4 sf = g4[i * 32 + l];     // self term
        float di = dinv[i];
        float4 b4 = ((const float4*)bias)[l];
        float4 r;
        r.x = fmaxf((acc.x + sf.x) * di + b4.x, 0.f);
        r.y = fmaxf((acc.y + sf.y) * di + b4.y, 0.f);
        r.z = fmaxf((acc.z + sf.z) * di + b4.z, 0.f);
        r.w = fmaxf((acc.w + sf.w) * di + b4.w, 0.f);
        ((float4*)h)[i * 32 + l] = r;
    }
}

// ---- Generic node GEMM: out[n,f] = (in[n,:] @ W[:,f]) * (dinv?) + (bias?)  W:[128,128] f32 ----

#define GEMM_NPB 64
__global__ __launch_bounds__(256) void k_gemm128(const float* __restrict__ W, const float* __restrict__ in,
                                                 const float* __restrict__ bias, const float* __restrict__ dinv,
                                                 float* __restrict__ out, int N) {
    __shared__ float Ws[D * 64];
    __shared__ float hs[GEMM_NPB * D];
    int t = threadIdx.x;
    int fbase = (blockIdx.x & 1) << 6;
    int base = (blockIdx.x >> 1) * GEMM_NPB;
    for (int i = t; i < D * 64; i += 256) {
        int k = i >> 6, fl = i & 63;
        Ws[i] = W[(k << 7) + fbase + fl];
    }
    for (int i = t; i < GEMM_NPB * D; i += 256) {
        int node = base + (i >> 7);
        hs[i] = (node < N) ? in[node * D + (i & 127)] : 0.f;
    }
    __syncthreads();
    int tf = (t & 15) << 2;
    int tj = (t >> 4) << 2;
    float acc[4][4];
#pragma unroll
    for (int a = 0; a < 4; ++a)
#pragma unroll
        for (int b = 0; b < 4; ++b) acc[a][b] = 0.f;
    for (int k = 0; k < D; k += 4) {
        float4 w[4];
        float4 hv[4];
#pragma unroll
        for (int kk = 0; kk < 4; ++kk) w[kk] = *(const float4*)&Ws[(k + kk) * 64 + tf];
#pragma unroll
        for (int j = 0; j < 4; ++j) hv[j] = *(const float4*)&hs[(tj + j) * D + k];
#pragma unroll
        for (int j = 0; j < 4; ++j) {
            float hk0 = hv[j].x, hk1 = hv[j].y, hk2 = hv[j].z, hk3 = hv[j].w;
            acc[j][0] += hk0 * w[0].x + hk1 * w[1].x + hk2 * w[2].x + hk3 * w[3].x;
            acc[j][1] += hk0 * w[0].y + hk1 * w[1].y + hk2 * w[2].y + hk3 * w[3].y;
            acc[j][2] += hk0 * w[0].z + hk1 * w[1].z + hk2 * w[2].z + hk3 * w[3].z;
            acc[j][3] += hk0 * w[0].w + hk1 * w[1].w + hk2 * w[2].w + hk3 * w[3].w;
        }
    }
    float bv0 = 0.f, bv1 = 0.f, bv2 = 0.f, bv3 = 0.f;
    if (bias) {
        bv0 = bias[fbase + tf + 0];
        bv1 = bias[fbase + tf + 1];
        bv2 = bias[fbase + tf + 2];
        bv3 = bias[fbase + tf + 3];
    }
#pragma unroll
    for (int j = 0; j < 4; ++j) {
        int node = base + tj + j;
        if (node >= N) continue;
        float sc = dinv ? dinv[node] : 1.0f;
        float4 o;
        o.x = acc[j][0] * sc + bv0;
        o.y = acc[j][1] * sc + bv1;
        o.z = acc[j][2] * sc + bv2;
        o.w = acc[j][3] * sc + bv3;
        *(float4*)&out[node * D + fbase + tf] = o;
    }
}

// ---- Edge output, CSR-ordered: one wave per dst node; c[d] in registers; 8 edges/batch,
//      8 lanes per edge (each lane owns 16 dims); 3-step reductions; scatter-write out[eid]. ----

__global__ __launch_bounds__(256) void k_edge(const float* __restrict__ a, const float* __restrict__ c,
                                              const int* __restrict__ rowstart, const int* __restrict__ col,
                                              const int* __restrict__ eid,
                                              const float* __restrict__ Wfin, const float* __restrict__ bfin,
                                              float* __restrict__ out, int N) {
    int wave = (blockIdx.x * blockDim.x + threadIdx.x) >> 6;
    int lane = threadIdx.x & 63;
    if (wave >= N) return;
    int d = wave;
    int g = lane >> 3;        // edge slot within batch (0..7)
    int r = lane & 7;         // 16-dim segment owner (0..7)

    // Wfin segment for dims [r*16, r*16+16): row-major [128][2]
    float wf0[16], wf1[16];
    const float4* wv = (const float4*)Wfin;
#pragma unroll
    for (int tq = 0; tq < 8; ++tq) {
        float4 m = wv[r * 8 + tq];            // {w0[k], w1[k], w0[k+1], w1[k+1]}
        wf0[2 * tq]     = m.x; wf1[2 * tq]     = m.y;
        wf0[2 * tq + 1] = m.z; wf1[2 * tq + 1] = m.w;
    }
    float bf0 = bfin[0], bf1 = bfin[1];

    const float4* a4 = (const float4*)a;
    const float4* c4 = (const float4*)c;
    float4 cv[4];
#pragma unroll
    for (int q = 0; q < 4; ++q) cv[q] = c4[d * 32 + r * 4 + q];

    int lo = rowstart[d], hi = rowstart[d + 1];
    for (int base = lo; base < hi; base += 8) {
        int idx = base + g;
        bool valid = idx < hi;
        int s = valid ? col[idx] : d;
        float p0 = 0.f, p1 = 0.f;
#pragma unroll
        for (int q = 0; q < 4; ++q) {
            float4 av = a4[s * 32 + r * 4 + q];
            float z0 = fmaxf(av.x + cv[q].x, 0.f);
            float z1 = fmaxf(av.y + cv[q].y, 0.f);
            float z2 = fmaxf(av.z + cv[q].z, 0.f);
            float z3 = fmaxf(av.w + cv[q].w, 0.f);
            p0 += z0 * wf0[4 * q] + z1 * wf0[4 * q + 1] + z2 * wf0[4 * q + 2] + z3 * wf0[4 * q + 3];
            p1 += z0 * wf1[4 * q] + z1 * wf1[4 * q + 1] + z2 * wf1[4 * q + 2] + z3 * wf1[4 * q + 3];
        }
        // reduce over r (8 lanes, stride-1 within group)
        p0 += __shfl_xor(p0, 1, 64);
        p0 += __shfl_xor(p0, 2, 64);
        p0 += __shfl_xor(p0, 4, 64);
        p1 += __shfl_xor(p1, 1, 64);
        p1 += __shfl_xor(p1, 2, 64);
        p1 += __shfl_xor(p1, 4, 64);
        if (r == 0 && valid) {
            int e = eid[idx];
            float l0 = p0 + bf0, l1 = p1 + bf1;
            float m = fmaxf(l0, l1);
            float lse = m + logf(expf(l0 - m) + expf(l1 - m));
            *((float2*)(out + 2 * (size_t)e)) = make_float2(l0 - lse, l1 - lse);
        }
    }
}

extern "C" void kernel_launch(void* const* d_in, const int* in_sizes, int n_in,
                              void* d_out, int out_size, void* d_ws, size_t ws_size,
                              hipStream_t stream) {
    const float* x     = (const float*)d_in[0];
    const int*   ei    = (const int*)d_in[1];
    const float* W1    = (const float*)d_in[2];
    const float* b1    = (const float*)d_in[3];
    const float* W2    = (const float*)d_in[4];
    const float* b2    = (const float*)d_in[5];
    const float* Wlin1 = (const float*)d_in[6];
    const float* blin1 = (const float*)d_in[7];
    const float* Wfin  = (const float*)d_in[8];
    const float* bfin  = (const float*)d_in[9];
    float* out = (float*)d_out;

    int N = in_sizes[0] / 8;
    int E = in_sizes[1] / 2;
    const int* src = ei;
    const int* dst = ei + E;

    char* w = (char*)d_ws;
    int* degi = (int*)w;      w += (size_t)N * 4;
    int* cursor = (int*)w;    w += (size_t)N * 4;
    int* rowstart = (int*)w;  w += (size_t)(N + 1) * 4;
    int* col = (int*)w;       w += (size_t)E * 4;
    int* eid = (int*)w;       w += (size_t)E * 4;
    float* dinv = (float*)w;  w += (size_t)N * 4;
    w = (char*)(((uintptr_t)w + 255) & ~(uintptr_t)255);
    float* buf0 = (float*)w;  w += (size_t)N * D * 4;
    float* buf1 = (float*)w;  w += (size_t)N * D * 4;
    float* buf2 = (float*)w;  w += (size_t)N * D * 4;

    hipMemsetAsync(degi, 0, (size_t)N * 8, stream);   // degi + cursor contiguous

    k_degree<<<(E + 255) / 256, 256, 0, stream>>>(dst, E, degi);
    k_dinv<<<(N + 255) / 256, 256, 0, stream>>>(degi, dinv, N);
    k_scan<<<1, 1024, 0, stream>>>(degi, rowstart, N);
    k_scatter<<<(E + 255) / 256, 256, 0, stream>>>(src, dst, E, rowstart, cursor, col, eid);

    // layer 1
    k_xform1<<<(N + 1) / 2, 256, 0, stream>>>(x, W1, dinv, buf0, N);
    k_agg<<<(N + 3) / 4, 256, 0, stream>>>(buf0, rowstart, col, dinv, b1, buf1, N);

    // layer 2
    int gblocks = ((N + GEMM_NPB - 1) / GEMM_NPB) * 2;
    k_gemm128<<<gblocks, 256, 0, stream>>>(W2, buf1, nullptr, dinv, buf0, N);
    k_agg<<<(N + 3) / 4, 256, 0, stream>>>(buf0, rowstart, col, dinv, b2, buf1, N);

    // edge MLP factorization
    k_gemm128<<<gblocks, 256, 0, stream>>>(Wlin1, buf1, nullptr, nullptr, buf0, N);
    k_gemm128<<<gblocks, 256, 0, stream>>>(Wlin1 + D * D, buf1, blin1, nullptr, buf2, N);

    k_edge<<<(N + 3) / 4, 256, 0, stream>>>(buf0, buf2, rowstart, col, eid, Wfin, bfin, out, N);
}

// Round 4
// 580.401 us; speedup vs baseline: 1.2393x; 1.2005x over previous
//
#include <hip/hip_runtime.h>
#include <stdint.h>
#include <math.h>

#define D 128

// bf16 pack/unpack (RNE)
__device__ __forceinline__ unsigned f2bf_pk(float a, float b) {
    union { float f; unsigned u; } x, y; x.f = a; y.f = b;
    unsigned ra = x.u + 0x7FFF + ((x.u >> 16) & 1);
    unsigned rb = y.u + 0x7FFF + ((y.u >> 16) & 1);
    return (ra >> 16) | (rb & 0xFFFF0000u);
}
__device__ __forceinline__ float2 bf2f2(unsigned u) {
    union { unsigned u; float f; } lo, hi;
    lo.u = u << 16; hi.u = u & 0xFFFF0000u;
    return make_float2(lo.f, hi.f);
}

// ---- Stage A: degree / dinv / CSR build ----

__global__ void k_degree(const int* __restrict__ dst, int E, int* __restrict__ degi) {
    int i = blockIdx.x * blockDim.x + threadIdx.x;
    if (i < E) atomicAdd(&degi[dst[i]], 1);
}

__global__ void k_dinv(const int* __restrict__ degi, float* __restrict__ dinv, int N) {
    int i = blockIdx.x * blockDim.x + threadIdx.x;
    if (i < N) dinv[i] = rsqrtf((float)degi[i] + 1.0f);
}

__global__ void k_scan(const int* __restrict__ degi, int* __restrict__ rowstart, int n) {
    __shared__ int sums[1024];
    int t = threadIdx.x;
    int chunk = (n + 1023) >> 10;
    if (chunk < 1) chunk = 1;
    int lo = t * chunk;
    int hi = lo + chunk; if (hi > n) hi = n;
    int s = 0;
    for (int i = lo; i < hi; ++i) s += degi[i];
    sums[t] = s;
    __syncthreads();
    for (int off = 1; off < 1024; off <<= 1) {
        int v = (t >= off) ? sums[t - off] : 0;
        __syncthreads();
        if (t >= off) sums[t] += v;
        __syncthreads();
    }
    int run = (t == 0) ? 0 : sums[t - 1];
    for (int i = lo; i < hi; ++i) { rowstart[i] = run; run += degi[i]; }
    if (hi == n) rowstart[n] = run;
}

__global__ void k_scatter(const int* __restrict__ src, const int* __restrict__ dst, int E,
                          const int* __restrict__ rowstart, int* __restrict__ cursor,
                          int* __restrict__ col, int* __restrict__ eid) {
    int i = blockIdx.x * blockDim.x + threadIdx.x;
    if (i < E) {
        int d = dst[i];
        int pos = rowstart[d] + atomicAdd(&cursor[d], 1);
        col[pos] = src[i];
        eid[pos] = i;
    }
}

// ---- layer-1 transform  g1 = bf16(dinv * (x @ W1)),  x:[N,8] f32 ----
// 256 threads = 4 nodes x 64 lanes; lane handles dims 2l, 2l+1

__global__ __launch_bounds__(256) void k_xform1(const float* __restrict__ x, const float* __restrict__ W1,
                                                const float* __restrict__ dinv, unsigned* __restrict__ g, int N) {
    __shared__ float Ws[8 * D];
    int t = threadIdx.x;
    for (int i = t; i < 8 * D; i += 256) Ws[i] = W1[i];
    __syncthreads();
    int node = blockIdx.x * 4 + (t >> 6);
    int l = t & 63;
    if (node < N) {
        float s0 = 0.f, s1 = 0.f;
#pragma unroll
        for (int k = 0; k < 8; ++k) {
            float xv = x[node * 8 + k];
            s0 += xv * Ws[k * D + 2 * l];
            s1 += xv * Ws[k * D + 2 * l + 1];
        }
        float di = dinv[node];
        g[node * 64 + l] = f2bf_pk(s0 * di, s1 * di);
    }
}

// ---- Aggregation: wave per node; 4 neighbors/batch, 16 lanes each own 8 dims (one uint4) ----
// h = relu(dinv*(self+sum) + b)  -> fp32 out

__global__ __launch_bounds__(256) void k_agg(const uint4* __restrict__ g, const int* __restrict__ rowstart,
                                             const int* __restrict__ col, const float* __restrict__ dinv,
                                             const float* __restrict__ bias, float* __restrict__ h, int N) {
    int wave = (blockIdx.x * blockDim.x + threadIdx.x) >> 6;
    int lane = threadIdx.x & 63;
    if (wave >= N) return;
    int i = wave;
    int sub = lane >> 4;      // neighbor slot 0..3
    int r = lane & 15;        // 8-dim segment owner
    float acc[8];
#pragma unroll
    for (int j = 0; j < 8; ++j) acc[j] = 0.f;
    int lo = rowstart[i], hi = rowstart[i + 1];
    int idx = lo + sub;
    bool v = idx < hi;
    int s = v ? col[idx] : 0;
    for (int base = lo; base < hi; base += 4) {
        int nidx = idx + 4;
        bool nv = nidx < hi;
        int ns = nv ? col[nidx] : 0;       // prefetch next batch's index
        if (v) {
            uint4 av = g[s * 16 + r];
            float2 p;
            p = bf2f2(av.x); acc[0] += p.x; acc[1] += p.y;
            p = bf2f2(av.y); acc[2] += p.x; acc[3] += p.y;
            p = bf2f2(av.z); acc[4] += p.x; acc[5] += p.y;
            p = bf2f2(av.w); acc[6] += p.x; acc[7] += p.y;
        }
        idx = nidx; s = ns; v = nv;
    }
#pragma unroll
    for (int j = 0; j < 8; ++j) {
        acc[j] += __shfl_xor(acc[j], 16, 64);
        acc[j] += __shfl_xor(acc[j], 32, 64);
    }
    if (sub == 0) {
        uint4 sv = g[i * 16 + r];   // self term
        float2 p;
        p = bf2f2(sv.x); acc[0] += p.x; acc[1] += p.y;
        p = bf2f2(sv.y); acc[2] += p.x; acc[3] += p.y;
        p = bf2f2(sv.z); acc[4] += p.x; acc[5] += p.y;
        p = bf2f2(sv.w); acc[6] += p.x; acc[7] += p.y;
        float di = dinv[i];
        float4 b0 = ((const float4*)bias)[r * 2];
        float4 b1 = ((const float4*)bias)[r * 2 + 1];
        float4 o0, o1;
        o0.x = fmaxf(acc[0] * di + b0.x, 0.f);
        o0.y = fmaxf(acc[1] * di + b0.y, 0.f);
        o0.z = fmaxf(acc[2] * di + b0.z, 0.f);
        o0.w = fmaxf(acc[3] * di + b0.w, 0.f);
        o1.x = fmaxf(acc[4] * di + b1.x, 0.f);
        o1.y = fmaxf(acc[5] * di + b1.y, 0.f);
        o1.z = fmaxf(acc[6] * di + b1.z, 0.f);
        o1.w = fmaxf(acc[7] * di + b1.w, 0.f);
        float4* hp = (float4*)(h + (size_t)i * D + r * 8);
        hp[0] = o0; hp[1] = o1;
    }
}

// ---- Node GEMM: out_bf16[n,f] = pack((in[n,:] @ W[:,f]) * (dinv?) + (bias?))  W:[128,128] f32 ----

#define GEMM_NPB 64
__global__ __launch_bounds__(256) void k_gemm128(const float* __restrict__ W, const float* __restrict__ in,
                                                 const float* __restrict__ bias, const float* __restrict__ dinv,
                                                 unsigned* __restrict__ out, int N) {
    __shared__ float Ws[D * 64];
    __shared__ float hs[GEMM_NPB * D];
    int t = threadIdx.x;
    int fbase = (blockIdx.x & 1) << 6;
    int base = (blockIdx.x >> 1) * GEMM_NPB;
    for (int i = t; i < D * 64; i += 256) {
        int k = i >> 6, fl = i & 63;
        Ws[i] = W[(k << 7) + fbase + fl];
    }
    for (int i = t; i < GEMM_NPB * D; i += 256) {
        int node = base + (i >> 7);
        hs[i] = (node < N) ? in[node * D + (i & 127)] : 0.f;
    }
    __syncthreads();
    int tf = (t & 15) << 2;
    int tj = (t >> 4) << 2;
    float acc[4][4];
#pragma unroll
    for (int a = 0; a < 4; ++a)
#pragma unroll
        for (int b = 0; b < 4; ++b) acc[a][b] = 0.f;
    for (int k = 0; k < D; k += 4) {
        float4 w[4];
        float4 hv[4];
#pragma unroll
        for (int kk = 0; kk < 4; ++kk) w[kk] = *(const float4*)&Ws[(k + kk) * 64 + tf];
#pragma unroll
        for (int j = 0; j < 4; ++j) hv[j] = *(const float4*)&hs[(tj + j) * D + k];
#pragma unroll
        for (int j = 0; j < 4; ++j) {
            float hk0 = hv[j].x, hk1 = hv[j].y, hk2 = hv[j].z, hk3 = hv[j].w;
            acc[j][0] += hk0 * w[0].x + hk1 * w[1].x + hk2 * w[2].x + hk3 * w[3].x;
            acc[j][1] += hk0 * w[0].y + hk1 * w[1].y + hk2 * w[2].y + hk3 * w[3].y;
            acc[j][2] += hk0 * w[0].z + hk1 * w[1].z + hk2 * w[2].z + hk3 * w[3].z;
            acc[j][3] += hk0 * w[0].w + hk1 * w[1].w + hk2 * w[2].w + hk3 * w[3].w;
        }
    }
    float bv0 = 0.f, bv1 = 0.f, bv2 = 0.f, bv3 = 0.f;
    if (bias) {
        bv0 = bias[fbase + tf + 0];
        bv1 = bias[fbase + tf + 1];
        bv2 = bias[fbase + tf + 2];
        bv3 = bias[fbase + tf + 3];
    }
#pragma unroll
    for (int j = 0; j < 4; ++j) {
        int node = base + tj + j;
        if (node >= N) continue;
        float sc = dinv ? dinv[node] : 1.0f;
        float o0 = acc[j][0] * sc + bv0;
        float o1 = acc[j][1] * sc + bv1;
        float o2 = acc[j][2] * sc + bv2;
        float o3 = acc[j][3] * sc + bv3;
        ((uint2*)out)[node * 32 + ((fbase + tf) >> 2)] = make_uint2(f2bf_pk(o0, o1), f2bf_pk(o2, o3));
    }
}

// ---- Edge output, CSR-ordered: wave per dst; c[d] in regs; 4 edges/batch, 16 lanes/edge ----

__global__ __launch_bounds__(256) void k_edge(const uint4* __restrict__ a, const uint4* __restrict__ c,
                                              const int* __restrict__ rowstart, const int* __restrict__ col,
                                              const int* __restrict__ eid,
                                              const float* __restrict__ Wfin, const float* __restrict__ bfin,
                                              float* __restrict__ out, int N) {
    int wave = (blockIdx.x * blockDim.x + threadIdx.x) >> 6;
    int lane = threadIdx.x & 63;
    if (wave >= N) return;
    int d = wave;
    int g = lane >> 4;        // edge slot 0..3
    int r = lane & 15;        // 8-dim segment owner

    // Wfin rows r*8 .. r*8+7 (row-major [128][2])
    float wf0[8], wf1[8];
    const float4* wv = (const float4*)Wfin;
#pragma unroll
    for (int q = 0; q < 4; ++q) {
        float4 m = wv[r * 4 + q];      // rows r*8+2q (m.x,m.y) and r*8+2q+1 (m.z,m.w)
        wf0[2 * q] = m.x; wf1[2 * q] = m.y;
        wf0[2 * q + 1] = m.z; wf1[2 * q + 1] = m.w;
    }
    float bf0 = bfin[0], bf1 = bfin[1];

    // c segment (bias already folded in by GEMM)
    float cf[8];
    {
        uint4 cv = c[d * 16 + r];
        float2 p;
        p = bf2f2(cv.x); cf[0] = p.x; cf[1] = p.y;
        p = bf2f2(cv.y); cf[2] = p.x; cf[3] = p.y;
        p = bf2f2(cv.z); cf[4] = p.x; cf[5] = p.y;
        p = bf2f2(cv.w); cf[6] = p.x; cf[7] = p.y;
    }

    int lo = rowstart[d], hi = rowstart[d + 1];
    int idx = lo + g;
    bool v = idx < hi;
    int s = v ? col[idx] : 0;
    for (int base = lo; base < hi; base += 4) {
        int nidx = idx + 4;
        bool nv = nidx < hi;
        int ns = nv ? col[nidx] : 0;   // prefetch next batch's col
        float p0 = 0.f, p1 = 0.f;
        uint4 av = a[s * 16 + r];
        float2 p;
        float z;
        p = bf2f2(av.x);
        z = fmaxf(p.x + cf[0], 0.f); p0 += z * wf0[0]; p1 += z * wf1[0];
        z = fmaxf(p.y + cf[1], 0.f); p0 += z * wf0[1]; p1 += z * wf1[1];
        p = bf2f2(av.y);
        z = fmaxf(p.x + cf[2], 0.f); p0 += z * wf0[2]; p1 += z * wf1[2];
        z = fmaxf(p.y + cf[3], 0.f); p0 += z * wf0[3]; p1 += z * wf1[3];
        p = bf2f2(av.z);
        z = fmaxf(p.x + cf[4], 0.f); p0 += z * wf0[4]; p1 += z * wf1[4];
        z = fmaxf(p.y + cf[5], 0.f); p0 += z * wf0[5]; p1 += z * wf1[5];
        p = bf2f2(av.w);
        z = fmaxf(p.x + cf[6], 0.f); p0 += z * wf0[6]; p1 += z * wf1[6];
        z = fmaxf(p.y + cf[7], 0.f); p0 += z * wf0[7]; p1 += z * wf1[7];
        // reduce over the 16-lane group (r bits 0..3)
        p0 += __shfl_xor(p0, 1, 64);
        p0 += __shfl_xor(p0, 2, 64);
        p0 += __shfl_xor(p0, 4, 64);
        p0 += __shfl_xor(p0, 8, 64);
        p1 += __shfl_xor(p1, 1, 64);
        p1 += __shfl_xor(p1, 2, 64);
        p1 += __shfl_xor(p1, 4, 64);
        p1 += __shfl_xor(p1, 8, 64);
        if (r == 0 && v) {
            int e = eid[idx];
            float l0 = p0 + bf0, l1 = p1 + bf1;
            float m = fmaxf(l0, l1);
            float lse = m + logf(expf(l0 - m) + expf(l1 - m));
            *((float2*)(out + 2 * (size_t)e)) = make_float2(l0 - lse, l1 - lse);
        }
        idx = nidx; s = ns; v = nv;
    }
}

extern "C" void kernel_launch(void* const* d_in, const int* in_sizes, int n_in,
                              void* d_out, int out_size, void* d_ws, size_t ws_size,
                              hipStream_t stream) {
    const float* x     = (const float*)d_in[0];
    const int*   ei    = (const int*)d_in[1];
    const float* W1    = (const float*)d_in[2];
    const float* b1    = (const float*)d_in[3];
    const float* W2    = (const float*)d_in[4];
    const float* b2    = (const float*)d_in[5];
    const float* Wlin1 = (const float*)d_in[6];
    const float* blin1 = (const float*)d_in[7];
    const float* Wfin  = (const float*)d_in[8];
    const float* bfin  = (const float*)d_in[9];
    float* out = (float*)d_out;

    int N = in_sizes[0] / 8;
    int E = in_sizes[1] / 2;
    const int* src = ei;
    const int* dst = ei + E;

    char* w = (char*)d_ws;
    int* degi = (int*)w;      w += (size_t)N * 4;
    int* cursor = (int*)w;    w += (size_t)N * 4;
    int* rowstart = (int*)w;  w += (size_t)(N + 1) * 4;
    int* col = (int*)w;       w += (size_t)E * 4;
    int* eid = (int*)w;       w += (size_t)E * 4;
    float* dinv = (float*)w;  w += (size_t)N * 4;
    w = (char*)(((uintptr_t)w + 255) & ~(uintptr_t)255);
    unsigned* bufG = (unsigned*)w; w += (size_t)N * 64 * 4;   // bf16-packed g1/g2
    float*    bufH = (float*)w;    w += (size_t)N * D * 4;    // fp32 h1/h2
    unsigned* bufA = (unsigned*)w; w += (size_t)N * 64 * 4;   // bf16-packed a
    unsigned* bufC = (unsigned*)w; w += (size_t)N * 64 * 4;   // bf16-packed c

    hipMemsetAsync(degi, 0, (size_t)N * 8, stream);   // degi + cursor contiguous

    k_degree<<<(E + 255) / 256, 256, 0, stream>>>(dst, E, degi);
    k_dinv<<<(N + 255) / 256, 256, 0, stream>>>(degi, dinv, N);
    k_scan<<<1, 1024, 0, stream>>>(degi, rowstart, N);
    k_scatter<<<(E + 255) / 256, 256, 0, stream>>>(src, dst, E, rowstart, cursor, col, eid);

    // layer 1
    k_xform1<<<(N + 3) / 4, 256, 0, stream>>>(x, W1, dinv, bufG, N);
    k_agg<<<(N + 3) / 4, 256, 0, stream>>>((const uint4*)bufG, rowstart, col, dinv, b1, bufH, N);

    // layer 2
    int gblocks = ((N + GEMM_NPB - 1) / GEMM_NPB) * 2;
    k_gemm128<<<gblocks, 256, 0, stream>>>(W2, bufH, nullptr, dinv, bufG, N);
    k_agg<<<(N + 3) / 4, 256, 0, stream>>>((const uint4*)bufG, rowstart, col, dinv, b2, bufH, N);

    // edge MLP factorization: a = h2@Wtop ; c = h2@Wbot + blin1
    k_gemm128<<<gblocks, 256, 0, stream>>>(Wlin1, bufH, nullptr, nullptr, bufA, N);
    k_gemm128<<<gblocks, 256, 0, stream>>>(Wlin1 + D * D, bufH, blin1, nullptr, bufC, N);

    k_edge<<<(N + 3) / 4, 256, 0, stream>>>((const uint4*)bufA, (const uint4*)bufC,
                                            rowstart, col, eid, Wfin, bfin, out, N);
}